// Round 1
// baseline (185.402 us; speedup 1.0000x reference)
//
#include <hip/hip_runtime.h>

// Sinkhorn OT loss: N=2048 frames, A=64 oscillators, B=513 bins, eps=0.01, 5 iters.
// Work in base-2 log domain: U = u/(eps*ln2)-style scaled duals, C2 = 100*log2(e).
// u-update: U[a] = Mu2[a] - LSE2_b(V[b] - C2*|f_a - bf_b|)   (u cancels analytically)
// v-update: V[b] = Nu2[b] - LSE2_a(U[a] - C2*|f_a - bf_b|)   (v cancels analytically)
// final:    total_n = sum_{a,b} 2^(U+V-C2*d) * d,  out = mean_n(total)

#define NN 2048
#define NA 64
#define NB 513
#define SINK_ITERS 5
#define C2 144.26950408889634f  // 100 * log2(e)

static __device__ __forceinline__ float EXP2(float x) {
#if __has_builtin(__builtin_amdgcn_exp2f)
    return __builtin_amdgcn_exp2f(x);   // raw v_exp_f32
#else
    return exp2f(x);
#endif
}
static __device__ __forceinline__ float LOG2(float x) {
#if __has_builtin(__builtin_amdgcn_logf)
    return __builtin_amdgcn_logf(x);    // raw v_log_f32
#else
    return __log2f(x);
#endif
}

static __device__ __forceinline__ float wave_sum(float v) {
#pragma unroll
    for (int o = 32; o > 0; o >>= 1) v += __shfl_xor(v, o);
    return v;
}

__global__ __launch_bounds__(64) void sinkhorn_kernel(
    const float* __restrict__ freqs, const float* __restrict__ amps,
    const float* __restrict__ spec, float* __restrict__ ws)
{
    const int n = blockIdx.x;
    const int l = threadIdx.x;  // lane 0..63

    __shared__ __align__(16) float V_s[NB];   // scaled dual v (base-2 units)
    __shared__ float Nu_s[NB];                // log2 of normalized target spec
    __shared__ float2 UF_s[NA];               // (U, f) pairs for v-pass broadcast

    const float f = freqs[n * NA + l];

    // ---- mu (base-2): log2( (clip(amp)+1e-9) / sum ) ----
    float amp = amps[n * NA + l];
    float ta = fminf(fmaxf(amp, 0.0f), 1e9f) + 1e-9f;
    float Sa = wave_sum(ta);
    float Mu2 = LOG2(ta / Sa);

    // ---- nu (base-2) + V init; lane l owns cols l, l+64, ..., (9 chunks) ----
    float tvv[9];
    float ps = 0.0f;
#pragma unroll
    for (int c = 0; c < 9; ++c) {
        int j = l + 64 * c;
        float x = (j < NB) ? spec[n * NB + j] : 0.0f;
        x = fminf(fmaxf(x, 0.0f), 1e9f) + 1e-9f;
        tvv[c] = x;
        ps += (j < NB) ? x : 0.0f;
    }
    float Snu = wave_sum(ps);
#pragma unroll
    for (int c = 0; c < 9; ++c) {
        int j = l + 64 * c;
        if (j < NB) { Nu_s[j] = LOG2(tvv[c] / Snu); V_s[j] = 0.0f; }
    }
    __syncthreads();

    // Pre-shifted row freqs so the bin accumulator advances once per float4.
    const float f0 = f, f1 = f - 15.625f, f2 = f - 31.25f, f3 = f - 46.875f;
    float U = 0.0f;
    const float4* V4 = reinterpret_cast<const float4*>(V_s);

    for (int it = 0; it < SINK_ITERS; ++it) {
        // ======== u-update: lane = row a, scan all 513 bins ========
        float m0 = -INFINITY, m1 = -INFINITY, m2 = -INFINITY, m3 = -INFINITY;
        float bf = 0.0f;
        for (int q = 0; q < 128; ++q) {
            float4 v = V4[q];
            m0 = fmaxf(m0, fmaf(-C2, fabsf(f0 - bf), v.x));
            m1 = fmaxf(m1, fmaf(-C2, fabsf(f1 - bf), v.y));
            m2 = fmaxf(m2, fmaf(-C2, fabsf(f2 - bf), v.z));
            m3 = fmaxf(m3, fmaf(-C2, fabsf(f3 - bf), v.w));
            bf += 62.5f;
        }
        float vt = V_s[512];
        float xt = fmaf(-C2, fabsf(f0 - 8000.0f), vt);
        float m = fmaxf(fmaxf(fmaxf(m0, m1), fmaxf(m2, m3)), xt);

        float s0 = 0.0f, s1 = 0.0f, s2 = 0.0f, s3 = 0.0f;
        bf = 0.0f;
        for (int q = 0; q < 128; ++q) {
            float4 v = V4[q];
            s0 += EXP2(fmaf(-C2, fabsf(f0 - bf), v.x) - m);
            s1 += EXP2(fmaf(-C2, fabsf(f1 - bf), v.y) - m);
            s2 += EXP2(fmaf(-C2, fabsf(f2 - bf), v.z) - m);
            s3 += EXP2(fmaf(-C2, fabsf(f3 - bf), v.w) - m);
            bf += 62.5f;
        }
        float ssum = ((s0 + s1) + (s2 + s3)) + EXP2(xt - m);
        U = Mu2 - m - LOG2(ssum);

        __syncthreads();               // v-pass reads of UF_s from prev iter done
        UF_s[l] = make_float2(U, f);
        __syncthreads();

        // ======== v-update: lane owns 9 cols, scan 64 rows ========
        float bfc[9];
#pragma unroll
        for (int c = 0; c < 9; ++c) bfc[c] = l * 15.625f + 1000.0f * c;

        float m9[9];
#pragma unroll
        for (int c = 0; c < 9; ++c) m9[c] = -INFINITY;
        for (int a = 0; a < NA; ++a) {
            float2 uf = UF_s[a];       // one ds_read_b64 broadcast
#pragma unroll
            for (int c = 0; c < 9; ++c)
                m9[c] = fmaxf(m9[c], fmaf(-C2, fabsf(uf.y - bfc[c]), uf.x));
        }
        float s9[9];
#pragma unroll
        for (int c = 0; c < 9; ++c) s9[c] = 0.0f;
        for (int a = 0; a < NA; ++a) {
            float2 uf = UF_s[a];
#pragma unroll
            for (int c = 0; c < 9; ++c)
                s9[c] += EXP2(fmaf(-C2, fabsf(uf.y - bfc[c]), uf.x) - m9[c]);
        }
        __syncthreads();               // u-pass reads of V_s done before overwrite
#pragma unroll
        for (int c = 0; c < 9; ++c) {
            int j = l + 64 * c;
            if (j < NB) V_s[j] = Nu_s[j] - m9[c] - LOG2(s9[c]);
        }
        __syncthreads();
    }

    // ======== final: total_n = sum_{a,b} 2^(U+V-C2*d) * d ========
    float t0 = 0.0f, t1 = 0.0f, t2 = 0.0f, t3 = 0.0f;
    float bf = 0.0f;
    for (int q = 0; q < 128; ++q) {
        float4 v = V4[q];
        float d0 = fabsf(f0 - bf);
        t0 = fmaf(EXP2(fmaf(-C2, d0, U + v.x)), d0, t0);
        float d1 = fabsf(f1 - bf);
        t1 = fmaf(EXP2(fmaf(-C2, d1, U + v.y)), d1, t1);
        float d2 = fabsf(f2 - bf);
        t2 = fmaf(EXP2(fmaf(-C2, d2, U + v.z)), d2, t2);
        float d3 = fabsf(f3 - bf);
        t3 = fmaf(EXP2(fmaf(-C2, d3, U + v.w)), d3, t3);
        bf += 62.5f;
    }
    float dtl = fabsf(f0 - 8000.0f);
    float tot = ((t0 + t1) + (t2 + t3)) + EXP2(fmaf(-C2, dtl, U + V_s[512])) * dtl;
    tot = wave_sum(tot);
    if (l == 0) ws[n] = tot;
}

// Deterministic second-stage reduction (no atomics -> bit-stable across replays).
__global__ __launch_bounds__(256) void reduce_kernel(
    const float* __restrict__ ws, float* __restrict__ out)
{
    __shared__ float sm[4];
    int t = threadIdx.x;
    float s = 0.0f;
    for (int i = t; i < NN; i += 256) s += ws[i];
    s = wave_sum(s);
    if ((t & 63) == 0) sm[t >> 6] = s;
    __syncthreads();
    if (t == 0) out[0] = (sm[0] + sm[1] + sm[2] + sm[3]) * (1.0f / 2048.0f);
}

extern "C" void kernel_launch(void* const* d_in, const int* in_sizes, int n_in,
                              void* d_out, int out_size, void* d_ws, size_t ws_size,
                              hipStream_t stream) {
    const float* freqs = (const float*)d_in[0];  // (2048,64)
    const float* amps  = (const float*)d_in[1];  // (2048,64)
    const float* spec  = (const float*)d_in[2];  // (2048,513)
    // d_in[3] = bin_freqs: arange(513)*15.625, exactly representable -> computed inline.
    float* ws = (float*)d_ws;                    // needs 2048*4 = 8 KB scratch

    sinkhorn_kernel<<<NN, 64, 0, stream>>>(freqs, amps, spec, ws);
    reduce_kernel<<<1, 256, 0, stream>>>(ws, (float*)d_out);
}

// Round 2
// 34.094 us; speedup vs baseline: 5.4380x; 5.4380x over previous
//
#include <hip/hip_runtime.h>

// Sinkhorn OT loss via prefix-LSE scans. N=2048 frames, A=64 osc, B=513 bins,
// eps=0.01 -> beta = 100*log2(e)*15.625 = 2254.21 per bin step.
// Key identity: lse_b(V[b] - beta*|t-b|) = lse( PL[b0] - beta*frac,
//   PR[b0+1] - beta*(1-frac) ), PL/PR = prefix/suffix lse-with-decay scans.
// Column LSEs use scans over oscillators sorted by t (bitonic, once/frame).
// Final sum pi*cost uses moment-augmented scans (log-weight, E[distance]).

#define NN 2048
#define NEGF (-1.0e30f)
#define BETA 2254.2110013890053f   // 100*log2(e)*15.625
#define SCALE 15.625f

static __device__ __forceinline__ float EXP2(float x) {
#if __has_builtin(__builtin_amdgcn_exp2f)
    return __builtin_amdgcn_exp2f(x);
#else
    return exp2f(x);
#endif
}
static __device__ __forceinline__ float LOG2(float x) {
#if __has_builtin(__builtin_amdgcn_logf)
    return __builtin_amdgcn_logf(x);
#else
    return __log2f(x);
#endif
}
static __device__ __forceinline__ float lse1(float x, float y) {
    float mx = fmaxf(x, y);
    float mn = fminf(x, y);
    return mx + LOG2(1.0f + EXP2(mn - mx));   // exact for mn==mx too
}
static __device__ __forceinline__ float wave_sum(float v) {
#pragma unroll
    for (int o = 32; o > 0; o >>= 1) v += __shfl_xor(v, o);
    return v;
}

__global__ __launch_bounds__(64) void sinkhorn_scan_kernel(
    const float* __restrict__ freqs, const float* __restrict__ amps,
    const float* __restrict__ spec, float* __restrict__ ws)
{
    const int n = blockIdx.x;
    const int l = threadIdx.x;   // lane 0..63

    __shared__ __align__(16) float PL_s[512];   // bin prefix-LSE (ref at bin b)
    __shared__ __align__(16) float PR_s[513];   // bin suffix-LSE (ref at bin b)
    __shared__ float tp_s[66];                  // sorted osc t, padded sentinels
    __shared__ float OPa[66], OSa[66];          // osc prefix/suffix scans (padded)
    __shared__ float OMa[66], OSMa[66];         // moment arrays (final pass)

    // ---- oscillator side ----
    float f   = freqs[n*64 + l];
    float amp = amps [n*64 + l];
    float ta  = fminf(fmaxf(amp, 0.0f), 1e9f) + 1e-9f;
    float Sa  = wave_sum(ta);
    float Mu2 = LOG2(ta / Sa);
    float t   = f * (1.0f / 15.625f);     // bin units, t in [0, 512)

    // bitonic sort (t, Mu2) ascending across the wave
#pragma unroll
    for (int k = 2; k <= 64; k <<= 1) {
#pragma unroll
        for (int j = k >> 1; j > 0; j >>= 1) {
            float ot = __shfl_xor(t, j);
            float om = __shfl_xor(Mu2, j);
            bool descBlock = (l & k) != 0;
            bool upper     = (l & j) != 0;
            bool takeMax   = upper != descBlock;
            bool otGreater = (ot > t) || (ot == t && om > Mu2);
            bool otSmaller = (ot < t) || (ot == t && om < Mu2);
            bool doTake = takeMax ? otGreater : otSmaller;
            t   = doTake ? ot : t;
            Mu2 = doTake ? om : Mu2;
        }
    }

    tp_s[1 + l] = t;
    if (l == 0) {
        tp_s[0] = 0.0f;  tp_s[65] = 20000.0f;
        OPa[0] = NEGF;   OPa[65] = NEGF;
        OSa[0] = NEGF;   OSa[65] = NEGF;
        OMa[0] = 0.0f;   OMa[65] = 0.0f;
        OSMa[0] = 0.0f;  OSMa[65] = 0.0f;
    }

    // ---- bin side: lane owns bins 8l..8l+7; bin 512 handled specially ----
    const float* sp = spec + n*513;
    float Nu8[8], V8[8], tv[8];
    float part = 0.0f;
#pragma unroll
    for (int i = 0; i < 8; ++i) {
        float x = sp[8*l + i];
        x = fminf(fmaxf(x, 0.0f), 1e9f) + 1e-9f;
        tv[i] = x; part += x;
    }
    float s512 = fminf(fmaxf(sp[512], 0.0f), 1e9f) + 1e-9f;
    float Snu = wave_sum(part) + s512;
    float iSnu = 1.0f / Snu;
#pragma unroll
    for (int i = 0; i < 8; ++i) { Nu8[i] = LOG2(tv[i] * iSnu); V8[i] = 0.0f; }
    float Nu512 = LOG2(s512 * iSnu);
    float V512 = 0.0f;

    __syncthreads();

    // per-bin tp-index of last osc with t <= b (0 = none). Fixed across iters.
    int jl8[8];
    {
        int j = 0;
#pragma unroll
        for (int i = 0; i < 8; ++i) {
            float b = (float)(8*l + i);
            while (j < 64 && tp_s[j+1] <= b) ++j;
            jl8[i] = j;
        }
    }

    float U = 0.0f;
#pragma unroll 1
    for (int it = 0; it < 5; ++it) {
        // ======== u-update: bin scans ========
        float Lloc[8], p4[8];
        float acc = V8[0]; Lloc[0] = acc;
#pragma unroll
        for (int i = 1; i < 8; ++i) { acc = lse1(acc - BETA, V8[i]); Lloc[i] = acc; }
        float T = acc;                         // ref at bin 8l+7
#pragma unroll
        for (int d = 1; d < 64; d <<= 1) {
            float o = __shfl_up(T, d);
            float cand = lse1(o - BETA*(8.0f*(float)d), T);
            T = (l >= d) ? cand : T;
        }
        float off = __shfl_up(T, 1);           // ref at bin 8l-1
        if (l == 0) off = NEGF;
#pragma unroll
        for (int i = 0; i < 8; ++i) p4[i] = lse1(off - BETA*(float)(i+1), Lloc[i]);
        *(float4*)&PL_s[8*l]     = make_float4(p4[0],p4[1],p4[2],p4[3]);
        *(float4*)&PL_s[8*l + 4] = make_float4(p4[4],p4[5],p4[6],p4[7]);

        float Rloc[8];
        float seed = (l == 63) ? V512 : NEGF;  // lane 63's block includes bin 512
        float racc = lse1(seed - BETA, V8[7]);
        Rloc[7] = racc;
#pragma unroll
        for (int i = 6; i >= 0; --i) { racc = lse1(racc - BETA, V8[i]); Rloc[i] = racc; }
        float Tr = racc;                       // ref at bin 8l
#pragma unroll
        for (int d = 1; d < 64; d <<= 1) {
            float o = __shfl_down(Tr, d);
            float cand = lse1(o - BETA*(8.0f*(float)d), Tr);
            Tr = (l + d < 64) ? cand : Tr;
        }
        float offr = __shfl_down(Tr, 1);       // ref at bin 8l+8
        if (l == 63) offr = NEGF;
#pragma unroll
        for (int i = 0; i < 8; ++i) p4[i] = lse1(offr - BETA*(float)(8-i), Rloc[i]);
        *(float4*)&PR_s[8*l]     = make_float4(p4[0],p4[1],p4[2],p4[3]);
        *(float4*)&PR_s[8*l + 4] = make_float4(p4[4],p4[5],p4[6],p4[7]);
        if (l == 63) PR_s[512] = V512;
        __syncthreads();

        // O(1) row query
        int b0 = (int)t; if (b0 > 511) b0 = 511;
        float frac = t - (float)b0;
        float EL = PL_s[b0]     - BETA*frac;
        float ER = PR_s[b0 + 1] - BETA*(1.0f - frac);
        U = Mu2 - lse1(EL, ER);

        // ======== v-update: osc scans (sorted order, variable gaps) ========
        float P = U;
#pragma unroll
        for (int d = 1; d < 64; d <<= 1) {
            float o  = __shfl_up(P, d);
            float td = __shfl_up(t, d);
            float cand = lse1(o - BETA*(t - td), P);
            P = (l >= d) ? cand : P;
        }
        float S = U;
#pragma unroll
        for (int d = 1; d < 64; d <<= 1) {
            float o  = __shfl_down(S, d);
            float td = __shfl_down(t, d);
            float cand = lse1(o - BETA*(td - t), S);
            S = (l + d < 64) ? cand : S;
        }
        OPa[1+l] = P; OSa[1+l] = S;
        __syncthreads();

        // O(1) per-bin queries
#pragma unroll
        for (int i = 0; i < 8; ++i) {
            float b = (float)(8*l + i);
            int iL = jl8[i], iR = jl8[i] + 1;
            float EL2 = OPa[iL] - BETA*(b - tp_s[iL]);
            float ER2 = OSa[iR] - BETA*(tp_s[iR] - b);
            V8[i] = Nu8[i] - lse1(EL2, ER2);
        }
        {   // bin 512: all osc are to the left (t < 512) -> iL=64, iR=65 sentinel
            float EL2 = OPa[64] - BETA*(512.0f - tp_s[64]);
            float ER2 = OSa[65] - BETA*(tp_s[65] - 512.0f);
            V512 = Nu512 - lse1(EL2, ER2);
        }
        // next iteration's PL/PR-write barrier orders these OPa/OSa reads
    }

    __syncthreads();   // 5th-iter OPa/OSa reads done before moment-scan writes

    // ======== final: total = sum_ab 2^(U+V-beta*d) * d * 15.625 ========
    float FL = U, MLm = 0.0f;   // (log-weight, E[t_ref - t_j]) left scan
#pragma unroll
    for (int d = 1; d < 64; d <<= 1) {
        float o  = __shfl_up(FL, d);
        float om = __shfl_up(MLm, d);
        float td = __shfl_up(t, d);
        float g  = t - td;
        float Lc = lse1(o - BETA*g, FL);
        float wa = EXP2(o - BETA*g - Lc);
        float wb = EXP2(FL - Lc);
        float Mc = wa*(om + g) + wb*MLm;
        if (l >= d) { FL = Lc; MLm = Mc; }
    }
    float FR = U, MRm = 0.0f;   // right scan
#pragma unroll
    for (int d = 1; d < 64; d <<= 1) {
        float o  = __shfl_down(FR, d);
        float om = __shfl_down(MRm, d);
        float td = __shfl_down(t, d);
        float g  = td - t;
        float Lc = lse1(o - BETA*g, FR);
        float wa = EXP2(o - BETA*g - Lc);
        float wb = EXP2(FR - Lc);
        float Mc = wa*(om + g) + wb*MRm;
        if (l + d < 64) { FR = Lc; MRm = Mc; }
    }
    OPa[1+l] = FL; OMa[1+l] = MLm;
    OSa[1+l] = FR; OSMa[1+l] = MRm;
    __syncthreads();

    float accT = 0.0f;
#pragma unroll
    for (int i = 0; i < 8; ++i) {
        float b = (float)(8*l + i);
        int iL = jl8[i], iR = jl8[i] + 1;
        float dL = b - tp_s[iL];
        float dR = tp_s[iR] - b;
        float cL = EXP2(V8[i] + (OPa[iL] - BETA*dL)) * (OMa[iL] + dL);
        float cR = EXP2(V8[i] + (OSa[iR] - BETA*dR)) * (OSMa[iR] + dR);
        accT += cL + cR;
    }
    if (l == 63) {   // bin 512 (right side empty -> sentinel contributes 0)
        float dL = 512.0f - tp_s[64];
        accT += EXP2(V512 + (OPa[64] - BETA*dL)) * (OMa[64] + dL);
    }
    float tot = wave_sum(accT) * SCALE;
    if (l == 0) ws[n] = tot;
}

// Deterministic second-stage reduction (no atomics -> bit-stable across replays).
__global__ __launch_bounds__(256) void reduce_kernel(
    const float* __restrict__ ws, float* __restrict__ out)
{
    __shared__ float sm[4];
    int tid = threadIdx.x;
    float s = 0.0f;
    for (int i = tid; i < NN; i += 256) s += ws[i];
    s = wave_sum(s);
    if ((tid & 63) == 0) sm[tid >> 6] = s;
    __syncthreads();
    if (tid == 0) out[0] = (sm[0] + sm[1] + sm[2] + sm[3]) * (1.0f / 2048.0f);
}

extern "C" void kernel_launch(void* const* d_in, const int* in_sizes, int n_in,
                              void* d_out, int out_size, void* d_ws, size_t ws_size,
                              hipStream_t stream) {
    const float* freqs = (const float*)d_in[0];  // (2048,64)
    const float* amps  = (const float*)d_in[1];  // (2048,64)
    const float* spec  = (const float*)d_in[2];  // (2048,513)
    // d_in[3] = bin_freqs (arange*15.625) -- computed inline in bin units.
    float* ws = (float*)d_ws;                    // 2048*4 B scratch

    sinkhorn_scan_kernel<<<NN, 64, 0, stream>>>(freqs, amps, spec, ws);
    reduce_kernel<<<1, 256, 0, stream>>>(ws, (float*)d_out);
}

// Round 3
// 27.739 us; speedup vs baseline: 6.6839x; 1.2291x over previous
//
#include <hip/hip_runtime.h>

// Sinkhorn OT loss via prefix-LSE scans, 2 waves per frame.
// N=2048 frames, A=64 osc, B=513 bins, eps=0.01.
// Base-2 log domain: beta = 100*log2(e)*15.625 per bin step.
// wave0: L-prefix bin scan + P osc scan; wave1: R-suffix bin scan + S osc scan.
// Bin ownership for V-update/final: wave w, lane l owns bins w*256 + 64c + l.
// LDS pad idx(b)=b+(b>>3) keeps stride-8 scan access <=2-way bank conflicts.

#define NN 2048
#define NEGF (-1.0e30f)
#define BETA 2254.2110013890053f          // 100*log2(e)*15.625
#define BETA8 18033.688011112042f          // 8*BETA
#define SCALE 15.625f

static __device__ __forceinline__ float EXP2(float x) {
#if __has_builtin(__builtin_amdgcn_exp2f)
    return __builtin_amdgcn_exp2f(x);
#else
    return exp2f(x);
#endif
}
static __device__ __forceinline__ float LOG2(float x) {
#if __has_builtin(__builtin_amdgcn_logf)
    return __builtin_amdgcn_logf(x);
#else
    return __log2f(x);
#endif
}
static __device__ __forceinline__ float lse1(float x, float y) {
    float mx = fmaxf(x, y);
    float mn = fminf(x, y);
    return mx + LOG2(1.0f + EXP2(mn - mx));
}
static __device__ __forceinline__ float wave_sum(float v) {
#pragma unroll
    for (int o = 32; o > 0; o >>= 1) v += __shfl_xor(v, o);
    return v;
}
static __device__ __forceinline__ int pidx(int b) { return b + (b >> 3); }

__global__ __launch_bounds__(128, 4) void sinkhorn2_kernel(
    const float* __restrict__ freqs, const float* __restrict__ amps,
    const float* __restrict__ spec, float* __restrict__ ws)
{
    const int n   = blockIdx.x;
    const int tid = threadIdx.x;
    const int w   = tid >> 6;
    const int l   = tid & 63;

    __shared__ float Vs[576];                 // padded V over bins 0..511
    __shared__ float PLloc[576];              // padded local L-prefix per bin
    __shared__ float PRloc[648];              // padded local R-suffix per bin (incl 512)
    __shared__ float TLa[65];                 // TLa[0]=NEGF, TLa[1+j]=cross L-prefix ref 8j+7
    __shared__ float TRa[66];                 // TRa[j]=cross R-suffix ref 8j; [64],[65]=NEGF
    __shared__ __align__(16) float ts_raw[64];
    __shared__ float2 sorted_tm[64];
    __shared__ float tp[66];                  // sorted t + sentinels
    __shared__ float OPa[66], OSa[66], OMa[66], OSMa[66];
    __shared__ float partial[2];

    // ---- inputs ----
    float f   = freqs[n*64 + l];
    float amp = amps [n*64 + l];
    float ta  = fminf(fmaxf(amp, 0.0f), 1e9f) + 1e-9f;
    float Sa  = wave_sum(ta);
    float Mu2 = LOG2(ta) - LOG2(Sa);
    float t   = f * (1.0f / 15.625f);         // bin units, t in [0,512)

    const float* sp = spec + n*513;
    const int baseb = w * 256;
    float tv[4];
    float part = 0.0f;
#pragma unroll
    for (int c = 0; c < 4; ++c) {
        float x = sp[baseb + c*64 + l];       // coalesced
        x = fminf(fmaxf(x, 0.0f), 1e9f) + 1e-9f;
        tv[c] = x; part += x;
    }
    float s512 = 0.0f;
    if (w == 1 && l == 63) { s512 = fminf(fmaxf(sp[512], 0.0f), 1e9f) + 1e-9f; part += s512; }
    part = wave_sum(part);
    if (l == 0) partial[w] = part;
    if (w == 0) ts_raw[l] = t;
    if (tid == 0) {
        tp[0] = 0.0f;  tp[65] = 20000.0f;
        TLa[0] = NEGF; TRa[64] = NEGF; TRa[65] = NEGF;
        OPa[0] = NEGF; OMa[0] = 0.0f;
        OSa[65] = NEGF; OSMa[65] = 0.0f;
    }
    __syncthreads();

    float lSnu = LOG2(partial[0] + partial[1]);
    float Nu4[4];
#pragma unroll
    for (int c = 0; c < 4; ++c) Nu4[c] = LOG2(tv[c]) - lSnu;
    float Nu512 = 0.0f, V512 = 0.0f;
    if (w == 1 && l == 63) Nu512 = LOG2(s512) - lSnu;

    // ---- rank sort (no dependent levels) ----
    int r = 0;
    const float4* t4 = (const float4*)ts_raw;
#pragma unroll
    for (int q = 0; q < 16; ++q) {
        float4 tt = t4[q];
        int j = 4*q;
        r += (tt.x < t) || (tt.x == t && (j+0) < l);
        r += (tt.y < t) || (tt.y == t && (j+1) < l);
        r += (tt.z < t) || (tt.z == t && (j+2) < l);
        r += (tt.w < t) || (tt.w == t && (j+3) < l);
    }
    if (w == 0) sorted_tm[r] = make_float2(t, Mu2);
#pragma unroll
    for (int c = 0; c < 4; ++c) Vs[pidx(baseb + c*64 + l)] = 0.0f;   // V init
    __syncthreads();

    float2 stm = sorted_tm[l];
    t = stm.x; Mu2 = stm.y;                  // lane = sorted osc index now
    if (w == 0) tp[1 + l] = t;
    __syncthreads();

    // ---- per-owned-bin osc split index via binary search (once) ----
    int jl4[4];
#pragma unroll
    for (int c = 0; c < 4; ++c) {
        float bf = (float)(baseb + c*64 + l);
        int lo = 0, hi = 65;
#pragma unroll
        for (int s = 0; s < 7; ++s) {
            int mid = (lo + hi) >> 1;
            bool le = (tp[mid] <= bf);
            lo = le ? mid : lo;
            hi = le ? hi : mid;
        }
        jl4[c] = lo;   // #osc with t <= bf
    }

    float U = 0.0f;
    float Vnew[4] = {0.0f, 0.0f, 0.0f, 0.0f};

#pragma unroll 1
    for (int it = 0; it < 5; ++it) {
        // ======== phase A: bin-axis scans (wave0 = L, wave1 = R) ========
        if (w == 0) {
            float v8[8];
#pragma unroll
            for (int i = 0; i < 8; ++i) v8[i] = Vs[9*l + i];
            float acc = v8[0];
            PLloc[9*l] = acc;
#pragma unroll
            for (int i = 1; i < 8; ++i) { acc = lse1(acc - BETA, v8[i]); PLloc[9*l + i] = acc; }
            float T = acc;                    // ref at bin 8l+7
#pragma unroll
            for (int d = 1; d < 64; d <<= 1) {
                float o = __shfl_up(T, d);
                float cand = lse1(o - BETA8*(float)d, T);
                T = (l >= d) ? cand : T;
            }
            TLa[1 + l] = T;
        } else {
            float v8[8];
#pragma unroll
            for (int i = 0; i < 8; ++i) v8[i] = Vs[9*l + i];
            float acc = (l == 63) ? lse1(V512 - BETA, v8[7]) : v8[7];
            PRloc[9*l + 7] = acc;
#pragma unroll
            for (int i = 6; i >= 0; --i) { acc = lse1(acc - BETA, v8[i]); PRloc[9*l + i] = acc; }
            if (l == 63) PRloc[pidx(512)] = V512;
            float T = acc;                    // ref at bin 8l
#pragma unroll
            for (int d = 1; d < 64; d <<= 1) {
                float o = __shfl_down(T, d);
                float cand = lse1(o - BETA8*(float)d, T);
                T = (l + d < 64) ? cand : T;
            }
            TRa[l] = T;
        }
        __syncthreads();

        // ======== U query (both waves redundantly; lane = sorted osc) ========
        {
            int b0 = (int)t; if (b0 > 511) b0 = 511;
            int blk = b0 >> 3;
            float a1 = TLa[blk]          - BETA*(t - (float)(8*blk - 1));
            float a2 = PLloc[pidx(b0)]   - BETA*(t - (float)b0);
            int b1 = b0 + 1;
            int blkR = b1 >> 3;
            float a3 = TRa[blkR + 1]     - BETA*((float)(8*(blkR + 1)) - t);
            float a4 = PRloc[pidx(b1)]   - BETA*((float)b1 - t);
            U = Mu2 - lse1(lse1(a1, a2), lse1(a3, a4));
        }

        // ======== phase B: osc-axis scans (wave0 = P, wave1 = S) ========
        if (w == 0) {
            float P = U;
#pragma unroll
            for (int d = 1; d < 64; d <<= 1) {
                float o  = __shfl_up(P, d);
                float td = __shfl_up(t, d);
                float cand = lse1(o - BETA*(t - td), P);
                P = (l >= d) ? cand : P;
            }
            OPa[1 + l] = P;
        } else {
            float S = U;
#pragma unroll
            for (int d = 1; d < 64; d <<= 1) {
                float o  = __shfl_down(S, d);
                float td = __shfl_down(t, d);
                float cand = lse1(o - BETA*(td - t), S);
                S = (l + d < 64) ? cand : S;
            }
            OSa[1 + l] = S;
        }
        __syncthreads();

        // ======== phase C: V update on owned bins ========
#pragma unroll
        for (int c = 0; c < 4; ++c) {
            float bf = (float)(baseb + c*64 + l);
            int iL = jl4[c], iR = iL + 1;
            float EL2 = OPa[iL] - BETA*(bf - tp[iL]);
            float ER2 = OSa[iR] - BETA*(tp[iR] - bf);
            Vnew[c] = Nu4[c] - lse1(EL2, ER2);
            Vs[pidx(baseb + c*64 + l)] = Vnew[c];
        }
        if (w == 1 && l == 63) {
            float EL2 = OPa[64] - BETA*(512.0f - tp[64]);
            float ER2 = OSa[65] - BETA*(tp[65] - 512.0f);
            V512 = Nu512 - lse1(EL2, ER2);
        }
        __syncthreads();
    }

    // ======== final: moment scans + per-bin contributions ========
    if (w == 0) {
        float F = U, M = 0.0f;
#pragma unroll
        for (int d = 1; d < 64; d <<= 1) {
            float o  = __shfl_up(F, d);
            float om = __shfl_up(M, d);
            float td = __shfl_up(t, d);
            float g  = t - td;
            float xo = o - BETA*g;
            float Lc = lse1(xo, F);
            float wa = EXP2(xo - Lc);
            float wb = EXP2(F - Lc);
            float Mc = wa*(om + g) + wb*M;
            if (l >= d) { F = Lc; M = Mc; }
        }
        OPa[1 + l] = F; OMa[1 + l] = M;
    } else {
        float F = U, M = 0.0f;
#pragma unroll
        for (int d = 1; d < 64; d <<= 1) {
            float o  = __shfl_down(F, d);
            float om = __shfl_down(M, d);
            float td = __shfl_down(t, d);
            float g  = td - t;
            float xo = o - BETA*g;
            float Lc = lse1(xo, F);
            float wa = EXP2(xo - Lc);
            float wb = EXP2(F - Lc);
            float Mc = wa*(om + g) + wb*M;
            if (l + d < 64) { F = Lc; M = Mc; }
        }
        OSa[1 + l] = F; OSMa[1 + l] = M;
    }
    __syncthreads();

    float accT = 0.0f;
#pragma unroll
    for (int c = 0; c < 4; ++c) {
        float bf = (float)(baseb + c*64 + l);
        int iL = jl4[c], iR = iL + 1;
        float dL = bf - tp[iL];
        float dR = tp[iR] - bf;
        accT += EXP2(Vnew[c] + (OPa[iL] - BETA*dL)) * (OMa[iL] + dL);
        accT += EXP2(Vnew[c] + (OSa[iR] - BETA*dR)) * (OSMa[iR] + dR);
    }
    if (w == 1 && l == 63) {
        float dL = 512.0f - tp[64];
        accT += EXP2(V512 + (OPa[64] - BETA*dL)) * (OMa[64] + dL);
    }
    accT = wave_sum(accT);
    if (l == 0) partial[w] = accT;
    __syncthreads();
    if (tid == 0) ws[n] = (partial[0] + partial[1]) * SCALE;
}

// Deterministic second-stage reduction (no atomics -> bit-stable across replays).
__global__ __launch_bounds__(256) void reduce_kernel(
    const float* __restrict__ ws, float* __restrict__ out)
{
    __shared__ float sm[4];
    int tid = threadIdx.x;
    float s = 0.0f;
    for (int i = tid; i < NN; i += 256) s += ws[i];
    s = wave_sum(s);
    if ((tid & 63) == 0) sm[tid >> 6] = s;
    __syncthreads();
    if (tid == 0) out[0] = (sm[0] + sm[1] + sm[2] + sm[3]) * (1.0f / 2048.0f);
}

extern "C" void kernel_launch(void* const* d_in, const int* in_sizes, int n_in,
                              void* d_out, int out_size, void* d_ws, size_t ws_size,
                              hipStream_t stream) {
    const float* freqs = (const float*)d_in[0];  // (2048,64)
    const float* amps  = (const float*)d_in[1];  // (2048,64)
    const float* spec  = (const float*)d_in[2];  // (2048,513)
    float* ws = (float*)d_ws;                    // 2048*4 B scratch

    sinkhorn2_kernel<<<NN, 128, 0, stream>>>(freqs, amps, spec, ws);
    reduce_kernel<<<1, 256, 0, stream>>>(ws, (float*)d_out);
}